// Round 2
// baseline (906.817 us; speedup 1.0000x reference)
//
#include <hip/hip_runtime.h>
#include <hip/hip_bf16.h>
#include <math.h>

typedef __bf16 bf16_t;
typedef __bf16 bf16x4 __attribute__((ext_vector_type(4)));
typedef __bf16 bf16x8 __attribute__((ext_vector_type(8)));
typedef float f32x4 __attribute__((ext_vector_type(4)));

#define AS1 __attribute__((address_space(1)))
#define AS3 __attribute__((address_space(3)))

__device__ __forceinline__ void gl_lds16(const bf16_t* g, bf16_t* l) {
  __builtin_amdgcn_global_load_lds((const AS1 void*)g, (AS3 void*)l, 16, 0, 0);
}

// ---------- block reductions (256 threads = 4 waves) ----------
__device__ __forceinline__ float block_sum_f(float v) {
  __shared__ float sb[4];
  #pragma unroll
  for (int o = 32; o; o >>= 1) v += __shfl_xor(v, o);
  if ((threadIdx.x & 63) == 0) sb[threadIdx.x >> 6] = v;
  __syncthreads();
  v = sb[0] + sb[1] + sb[2] + sb[3];
  __syncthreads();
  return v;
}
__device__ __forceinline__ float block_max_f(float v) {
  __shared__ float sm[4];
  #pragma unroll
  for (int o = 32; o; o >>= 1) v = fmaxf(v, __shfl_xor(v, o));
  if ((threadIdx.x & 63) == 0) sm[threadIdx.x >> 6] = v;
  __syncthreads();
  v = fmaxf(fmaxf(sm[0], sm[1]), fmaxf(sm[2], sm[3]));
  __syncthreads();
  return v;
}

// ---------- weight absmean (f64 accumulation, two-pass, deterministic) ----------
__global__ __launch_bounds__(256) void wabs_partial(const float* __restrict__ w, int n4,
                                                    double* __restrict__ part) {
  const float4* w4 = (const float4*)w;
  double s = 0.0;
  const int stride = gridDim.x * blockDim.x;
  for (int i = blockIdx.x * blockDim.x + threadIdx.x; i < n4; i += stride) {
    float4 v = w4[i];
    s += (double)fabsf(v.x) + (double)fabsf(v.y) + (double)fabsf(v.z) + (double)fabsf(v.w);
  }
  #pragma unroll
  for (int o = 32; o; o >>= 1) s += __shfl_xor(s, o);
  __shared__ double sd[4];
  if ((threadIdx.x & 63) == 0) sd[threadIdx.x >> 6] = s;
  __syncthreads();
  if (threadIdx.x == 0) part[blockIdx.x] = sd[0] + sd[1] + sd[2] + sd[3];
}

__global__ __launch_bounds__(256) void wabs_final(const double* __restrict__ part, int np,
                                                  double n, float* __restrict__ fwout) {
  double s = 0.0;
  for (int i = threadIdx.x; i < np; i += blockDim.x) s += part[i];
  #pragma unroll
  for (int o = 32; o; o >>= 1) s += __shfl_xor(s, o);
  __shared__ double sd[4];
  if ((threadIdx.x & 63) == 0) sd[threadIdx.x >> 6] = s;
  __syncthreads();
  if (threadIdx.x == 0) {
    double mean = (sd[0] + sd[1] + sd[2] + sd[3]) / n;
    fwout[0] = (float)fmax(mean, 1e-5);  // dequant factor = clip(mean|w|, 1e-5)
  }
}

// ---------- ternary weight quantization: tern = clip(rint(w/fw), -1, 1) as bf16 ----------
__global__ __launch_bounds__(256) void quant_w(const float* __restrict__ w,
                                               const float* __restrict__ fw,
                                               bf16_t* __restrict__ wq, int n4) {
  int i = blockIdx.x * blockDim.x + threadIdx.x;
  if (i >= n4) return;
  const float s = 1.0f / fw[0];
  float4 v = ((const float4*)w)[i];
  bf16x4 q;
  q[0] = (bf16_t)fminf(fmaxf(rintf(v.x * s), -1.f), 1.f);
  q[1] = (bf16_t)fminf(fmaxf(rintf(v.y * s), -1.f), 1.f);
  q[2] = (bf16_t)fminf(fmaxf(rintf(v.z * s), -1.f), 1.f);
  q[3] = (bf16_t)fminf(fmaxf(rintf(v.w * s), -1.f), 1.f);
  ((bf16x4*)wq)[i] = q;
}

// ---------- rms_norm + act_quant of x rows (K = 2048), one block per row ----------
__global__ __launch_bounds__(256) void rms_quant_x(const float* __restrict__ x,
                                                   bf16_t* __restrict__ xq,
                                                   float* __restrict__ fx, int K) {
  const int row = blockIdx.x, t = threadIdx.x;
  const size_t base = (size_t)row * K;
  float v[8];
  float ss = 0.f;
  #pragma unroll
  for (int j = 0; j < 2; j++) {
    float4 lv = *(const float4*)(x + base + j * 1024 + t * 4);
    v[j*4+0] = lv.x; v[j*4+1] = lv.y; v[j*4+2] = lv.z; v[j*4+3] = lv.w;
  }
  #pragma unroll
  for (int i = 0; i < 8; i++) ss += v[i] * v[i];
  ss = block_sum_f(ss);
  const float r = 1.0f / sqrtf(ss / (float)K + 1e-5f);
  float amax = 0.f;
  #pragma unroll
  for (int i = 0; i < 8; i++) { v[i] *= r; amax = fmaxf(amax, fabsf(v[i])); }
  amax = block_max_f(amax);
  amax = fmaxf(amax, 1e-5f);
  const float scale = 127.0f / amax;
  #pragma unroll
  for (int j = 0; j < 2; j++) {
    bf16x4 q;
    #pragma unroll
    for (int e = 0; e < 4; e++)
      q[e] = (bf16_t)fminf(fmaxf(rintf(v[j*4+e] * scale), -128.f), 127.f);
    *(bf16x4*)(xq + base + j * 1024 + t * 4) = q;
  }
  if (t == 0) fx[row] = amax / 127.0f;
}

// ---------- LayerNorm -> rms_norm -> act_quant, IN-PLACE on bf16 h rows (N = 8192) ----
// One block per row; each thread reads its 32 elements into registers before the first
// reduction barrier, writes after all reductions -> in-place safe.
__global__ __launch_bounds__(256) void ln_rms_quant(bf16_t* h,
                                                    const float* __restrict__ g,
                                                    const float* __restrict__ bb,
                                                    float* __restrict__ fh, int N) {
  const int row = blockIdx.x, t = threadIdx.x;
  const size_t base = (size_t)row * N;
  float v[32];
  float s = 0.f, ss = 0.f;
  #pragma unroll
  for (int j = 0; j < 8; j++) {
    const int col = j * 1024 + t * 4;
    bf16x4 q = *(const bf16x4*)(h + base + col);
    v[j*4+0] = (float)q[0]; v[j*4+1] = (float)q[1];
    v[j*4+2] = (float)q[2]; v[j*4+3] = (float)q[3];
  }
  #pragma unroll
  for (int i = 0; i < 32; i++) { s += v[i]; ss += v[i] * v[i]; }
  s = block_sum_f(s);
  ss = block_sum_f(ss);
  const float mu = s / (float)N;
  const float var = ss / (float)N - mu * mu;
  const float rstd = 1.0f / sqrtf(var + 1e-5f);
  float ss2 = 0.f;
  #pragma unroll
  for (int j = 0; j < 8; j++) {
    const int col = j * 1024 + t * 4;
    float4 gv = *(const float4*)(g + col);
    float4 bv = *(const float4*)(bb + col);
    float y0 = (v[j*4+0] - mu) * rstd * gv.x + bv.x;
    float y1 = (v[j*4+1] - mu) * rstd * gv.y + bv.y;
    float y2 = (v[j*4+2] - mu) * rstd * gv.z + bv.z;
    float y3 = (v[j*4+3] - mu) * rstd * gv.w + bv.w;
    v[j*4+0] = y0; v[j*4+1] = y1; v[j*4+2] = y2; v[j*4+3] = y3;
    ss2 += y0*y0 + y1*y1 + y2*y2 + y3*y3;
  }
  ss2 = block_sum_f(ss2);
  const float r2 = 1.0f / sqrtf(ss2 / (float)N + 1e-5f);
  float amax = 0.f;
  #pragma unroll
  for (int i = 0; i < 32; i++) { v[i] *= r2; amax = fmaxf(amax, fabsf(v[i])); }
  amax = block_max_f(amax);
  amax = fmaxf(amax, 1e-5f);
  const float scale = 127.0f / amax;
  #pragma unroll
  for (int j = 0; j < 8; j++) {
    const int col = j * 1024 + t * 4;
    bf16x4 q;
    #pragma unroll
    for (int e = 0; e < 4; e++)
      q[e] = (bf16_t)fminf(fmaxf(rintf(v[j*4+e] * scale), -128.f), 127.f);
    *(bf16x4*)(h + base + col) = q;
  }
  if (t == 0) fh[row] = amax / 127.0f;
}

// ---------- bf16 GEMM, B stored [N][K] (B^T form). m97 structure: 128x128 tile,
// 4 waves x (4x4) 16x16x32 frags, global_load_lds width 16.
// EPI: 1 = dequant+bias+SiLU+GELU(exact), 0 = dequant+bias only.
template<int EPI, bool STORE_BF16>
__global__ __launch_bounds__(256) void gemm_bt(const bf16_t* __restrict__ A,
                                               const bf16_t* __restrict__ B,
                                               const float* __restrict__ rowf,
                                               const float* __restrict__ wf,
                                               const float* __restrict__ bias,
                                               float* __restrict__ Cf,
                                               bf16_t* __restrict__ Cb,
                                               int M, int N, int K) {
  __shared__ bf16_t lA[128 * 32];
  __shared__ bf16_t lB[128 * 32];
  const int tid = threadIdx.x;
  const int w = tid >> 6, lane = tid & 63;
  const int ntile = N >> 7;
  const int bm = blockIdx.x / ntile, bn = blockIdx.x % ntile;
  const int tm = bm << 7, tn = bn << 7;
  const int wr = w >> 1, wc = w & 1;
  const int ln15 = lane & 15;
  const int lk = (lane >> 4) << 3;       // k element offset within 32: 0,8,16,24
  const int rq = (lane >> 4) << 2;       // C/D row quad: 0,4,8,12

  // staging: tile is 128 rows x 64 bytes; chunk (w*2+i) covers bytes [chunk*1024, +1024)
  const int off0 = (w * 2 + 0) * 1024 + lane * 16;
  const int off1 = (w * 2 + 1) * 1024 + lane * 16;
  const int r0 = off0 >> 6, c0 = (off0 & 63) >> 1;
  const int r1 = off1 >> 6, c1 = (off1 & 63) >> 1;
  const bf16_t* a0 = A + (size_t)(tm + r0) * K + c0;
  const bf16_t* a1 = A + (size_t)(tm + r1) * K + c1;
  const bf16_t* b0 = B + (size_t)(tn + r0) * K + c0;
  const bf16_t* b1 = B + (size_t)(tn + r1) * K + c1;
  bf16_t* lA0 = &lA[(w * 2 + 0) * 512];
  bf16_t* lA1 = &lA[(w * 2 + 1) * 512];
  bf16_t* lB0 = &lB[(w * 2 + 0) * 512];
  bf16_t* lB1 = &lB[(w * 2 + 1) * 512];

  f32x4 acc[4][4] = {};

  for (int k0 = 0; k0 < K; k0 += 32) {
    gl_lds16(a0 + k0, lA0);
    gl_lds16(a1 + k0, lA1);
    gl_lds16(b0 + k0, lB0);
    gl_lds16(b1 + k0, lB1);
    __syncthreads();
    bf16x8 af[4], bfr[4];
    #pragma unroll
    for (int m = 0; m < 4; m++)
      af[m] = *(const bf16x8*)&lA[(wr * 64 + m * 16 + ln15) * 32 + lk];
    #pragma unroll
    for (int n = 0; n < 4; n++)
      bfr[n] = *(const bf16x8*)&lB[(wc * 64 + n * 16 + ln15) * 32 + lk];
    #pragma unroll
    for (int m = 0; m < 4; m++)
      #pragma unroll
      for (int n = 0; n < 4; n++)
        acc[m][n] = __builtin_amdgcn_mfma_f32_16x16x32_bf16(af[m], bfr[n], acc[m][n], 0, 0, 0);
    __syncthreads();
  }

  // epilogue: C[row][col] = acc * fx[row]*fw + bias[col]  (+ SiLU+GELU for EPI==1)
  const float fwv = wf[0];
  float rsc[4][4];
  #pragma unroll
  for (int m = 0; m < 4; m++)
    #pragma unroll
    for (int r = 0; r < 4; r++)
      rsc[m][r] = rowf[tm + wr * 64 + m * 16 + rq + r] * fwv;

  #pragma unroll
  for (int m = 0; m < 4; m++) {
    #pragma unroll
    for (int n = 0; n < 4; n++) {
      const int col = tn + wc * 64 + n * 16 + ln15;
      const float bv = bias[col];
      #pragma unroll
      for (int r = 0; r < 4; r++) {
        const int row = tm + wr * 64 + m * 16 + rq + r;
        float val = acc[m][n][r] * rsc[m][r] + bv;
        if (EPI == 1) {
          float sl = val / (1.0f + expf(-val));                      // SiLU
          val = 0.5f * sl * (1.0f + erff(sl * 0.70710678118654752f)); // exact GELU
        }
        if (STORE_BF16) Cb[(size_t)row * N + col] = (bf16_t)val;
        else            Cf[(size_t)row * N + col] = val;
      }
    }
  }
}

extern "C" void kernel_launch(void* const* d_in, const int* in_sizes, int n_in,
                              void* d_out, int out_size, void* d_ws, size_t ws_size,
                              hipStream_t stream) {
  const float* x   = (const float*)d_in[0];
  const float* w1  = (const float*)d_in[1];
  const float* b1  = (const float*)d_in[2];
  const float* lng = (const float*)d_in[3];
  const float* lnb = (const float*)d_in[4];
  const float* w2  = (const float*)d_in[5];
  const float* b2  = (const float*)d_in[6];
  float* out = (float*)d_out;

  const int inner = in_sizes[2];           // 8192
  const int d     = in_sizes[1] / inner;   // 2048
  const int M     = in_sizes[0] / d;       // 8192 (= B*S)

  // ---- workspace layout: small buffers first, big activations last ----
  char* ws = (char*)d_ws;
  size_t off = 0;
  double* part = (double*)(ws + off); off += 1024 * 8;
  float*  fw   = (float*)(ws + off);  off += 256;
  float*  fx   = (float*)(ws + off);  off += (size_t)M * 4;
  float*  fh   = (float*)(ws + off);  off += (size_t)M * 4;
  bf16_t* w1q  = (bf16_t*)(ws + off); off += (size_t)inner * d * 2;
  bf16_t* w2q  = (bf16_t*)(ws + off); off += (size_t)inner * d * 2;

  // M-chunk size: largest power-of-two (multiple of 128, <= M) whose xq+hq fit.
  int MC = M;
  while (MC > 128 && off + (size_t)MC * (size_t)(d + inner) * 2 > ws_size) MC >>= 1;
  bf16_t* xq = (bf16_t*)(ws + off); off += (size_t)MC * d * 2;
  bf16_t* hq = (bf16_t*)(ws + off);

  const int nw = inner * d;
  const int n4 = nw / 4;

  // weight scales (global absmean, f64 two-pass) + ternary quant (chunk-independent)
  wabs_partial<<<1024, 256, 0, stream>>>(w1, n4, part);
  wabs_final<<<1, 256, 0, stream>>>(part, 1024, (double)nw, fw + 0);
  wabs_partial<<<1024, 256, 0, stream>>>(w2, n4, part);
  wabs_final<<<1, 256, 0, stream>>>(part, 1024, (double)nw, fw + 1);
  quant_w<<<n4 / 256, 256, 0, stream>>>(w1, fw + 0, w1q, n4);
  quant_w<<<n4 / 256, 256, 0, stream>>>(w2, fw + 1, w2q, n4);

  for (int mc = 0; mc < M; mc += MC) {
    // x rows -> rms_norm -> int8-valued bf16 + per-row scale
    rms_quant_x<<<MC, 256, 0, stream>>>(x + (size_t)mc * d, xq, fx, d);

    // GEMM1 + fused SiLU+GELU epilogue -> h (bf16, into hq buffer)
    const int g1 = (MC / 128) * (inner / 128);
    gemm_bt<1, true><<<g1, 256, 0, stream>>>(xq, w1q, fx, fw + 0, b1,
                                             nullptr, hq, MC, inner, d);

    // LayerNorm -> rms_norm -> act_quant, in place on hq
    ln_rms_quant<<<MC, 256, 0, stream>>>(hq, lng, lnb, fh, inner);

    // GEMM2 -> out rows (f32)
    const int g2 = (MC / 128) * (d / 128);
    gemm_bt<0, false><<<g2, 256, 0, stream>>>(hq, w2q, fh, fw + 1, b2,
                                              out + (size_t)mc * d, nullptr, MC, d, inner);
  }
}

// Round 3
// 845.665 us; speedup vs baseline: 1.0723x; 1.0723x over previous
//
#include <hip/hip_runtime.h>
#include <hip/hip_bf16.h>
#include <math.h>

typedef __bf16 bf16_t;
typedef __bf16 bf16x4 __attribute__((ext_vector_type(4)));
typedef __bf16 bf16x8 __attribute__((ext_vector_type(8)));
typedef float f32x4 __attribute__((ext_vector_type(4)));

#define AS1 __attribute__((address_space(1)))
#define AS3 __attribute__((address_space(3)))

__device__ __forceinline__ void gl_lds16(const bf16_t* g, bf16_t* l) {
  __builtin_amdgcn_global_load_lds((const AS1 void*)g, (AS3 void*)l, 16, 0, 0);
}

// ---------- block reductions (256 threads = 4 waves) ----------
__device__ __forceinline__ float block_sum_f(float v) {
  __shared__ float sb[4];
  #pragma unroll
  for (int o = 32; o; o >>= 1) v += __shfl_xor(v, o);
  if ((threadIdx.x & 63) == 0) sb[threadIdx.x >> 6] = v;
  __syncthreads();
  v = sb[0] + sb[1] + sb[2] + sb[3];
  __syncthreads();
  return v;
}
__device__ __forceinline__ float block_max_f(float v) {
  __shared__ float sm[4];
  #pragma unroll
  for (int o = 32; o; o >>= 1) v = fmaxf(v, __shfl_xor(v, o));
  if ((threadIdx.x & 63) == 0) sm[threadIdx.x >> 6] = v;
  __syncthreads();
  v = fmaxf(fmaxf(sm[0], sm[1]), fmaxf(sm[2], sm[3]));
  __syncthreads();
  return v;
}

// ---------- weight absmean (f64 accumulation, two-pass, deterministic) ----------
__global__ __launch_bounds__(256) void wabs_partial(const float* __restrict__ w, int n4,
                                                    double* __restrict__ part) {
  const float4* w4 = (const float4*)w;
  double s = 0.0;
  const int stride = gridDim.x * blockDim.x;
  for (int i = blockIdx.x * blockDim.x + threadIdx.x; i < n4; i += stride) {
    float4 v = w4[i];
    s += (double)fabsf(v.x) + (double)fabsf(v.y) + (double)fabsf(v.z) + (double)fabsf(v.w);
  }
  #pragma unroll
  for (int o = 32; o; o >>= 1) s += __shfl_xor(s, o);
  __shared__ double sd[4];
  if ((threadIdx.x & 63) == 0) sd[threadIdx.x >> 6] = s;
  __syncthreads();
  if (threadIdx.x == 0) part[blockIdx.x] = sd[0] + sd[1] + sd[2] + sd[3];
}

__global__ __launch_bounds__(256) void wabs_final(const double* __restrict__ part, int np,
                                                  double n, float* __restrict__ fwout) {
  double s = 0.0;
  for (int i = threadIdx.x; i < np; i += blockDim.x) s += part[i];
  #pragma unroll
  for (int o = 32; o; o >>= 1) s += __shfl_xor(s, o);
  __shared__ double sd[4];
  if ((threadIdx.x & 63) == 0) sd[threadIdx.x >> 6] = s;
  __syncthreads();
  if (threadIdx.x == 0) {
    double mean = (sd[0] + sd[1] + sd[2] + sd[3]) / n;
    fwout[0] = (float)fmax(mean, 1e-5);
  }
}

// ---------- ternary weight quantization ----------
__global__ __launch_bounds__(256) void quant_w(const float* __restrict__ w,
                                               const float* __restrict__ fw,
                                               bf16_t* __restrict__ wq, int n4) {
  int i = blockIdx.x * blockDim.x + threadIdx.x;
  if (i >= n4) return;
  const float s = 1.0f / fw[0];
  float4 v = ((const float4*)w)[i];
  bf16x4 q;
  q[0] = (bf16_t)fminf(fmaxf(rintf(v.x * s), -1.f), 1.f);
  q[1] = (bf16_t)fminf(fmaxf(rintf(v.y * s), -1.f), 1.f);
  q[2] = (bf16_t)fminf(fmaxf(rintf(v.z * s), -1.f), 1.f);
  q[3] = (bf16_t)fminf(fmaxf(rintf(v.w * s), -1.f), 1.f);
  ((bf16x4*)wq)[i] = q;
}

// ---------- rms_norm + act_quant of x rows (K = 2048) ----------
__global__ __launch_bounds__(256) void rms_quant_x(const float* __restrict__ x,
                                                   bf16_t* __restrict__ xq,
                                                   float* __restrict__ fx, int K) {
  const int row = blockIdx.x, t = threadIdx.x;
  const size_t base = (size_t)row * K;
  float v[8];
  float ss = 0.f;
  #pragma unroll
  for (int j = 0; j < 2; j++) {
    float4 lv = *(const float4*)(x + base + j * 1024 + t * 4);
    v[j*4+0] = lv.x; v[j*4+1] = lv.y; v[j*4+2] = lv.z; v[j*4+3] = lv.w;
  }
  #pragma unroll
  for (int i = 0; i < 8; i++) ss += v[i] * v[i];
  ss = block_sum_f(ss);
  const float r = 1.0f / sqrtf(ss / (float)K + 1e-5f);
  float amax = 0.f;
  #pragma unroll
  for (int i = 0; i < 8; i++) { v[i] *= r; amax = fmaxf(amax, fabsf(v[i])); }
  amax = block_max_f(amax);
  amax = fmaxf(amax, 1e-5f);
  const float scale = 127.0f / amax;
  #pragma unroll
  for (int j = 0; j < 2; j++) {
    bf16x4 q;
    #pragma unroll
    for (int e = 0; e < 4; e++)
      q[e] = (bf16_t)fminf(fmaxf(rintf(v[j*4+e] * scale), -128.f), 127.f);
    *(bf16x4*)(xq + base + j * 1024 + t * 4) = q;
  }
  if (t == 0) fx[row] = amax / 127.0f;
}

// ---------- LayerNorm -> rms_norm -> act_quant, IN-PLACE on bf16 h rows (N = 8192) ----
__global__ __launch_bounds__(256) void ln_rms_quant(bf16_t* h,
                                                    const float* __restrict__ g,
                                                    const float* __restrict__ bb,
                                                    float* __restrict__ fh, int N) {
  const int row = blockIdx.x, t = threadIdx.x;
  const size_t base = (size_t)row * N;
  float v[32];
  float s = 0.f, ss = 0.f;
  #pragma unroll
  for (int j = 0; j < 8; j++) {
    const int col = j * 1024 + t * 4;
    bf16x4 q = *(const bf16x4*)(h + base + col);
    v[j*4+0] = (float)q[0]; v[j*4+1] = (float)q[1];
    v[j*4+2] = (float)q[2]; v[j*4+3] = (float)q[3];
  }
  #pragma unroll
  for (int i = 0; i < 32; i++) { s += v[i]; ss += v[i] * v[i]; }
  s = block_sum_f(s);
  ss = block_sum_f(ss);
  const float mu = s / (float)N;
  const float var = ss / (float)N - mu * mu;
  const float rstd = 1.0f / sqrtf(var + 1e-5f);
  float ss2 = 0.f;
  #pragma unroll
  for (int j = 0; j < 8; j++) {
    const int col = j * 1024 + t * 4;
    float4 gv = *(const float4*)(g + col);
    float4 bv = *(const float4*)(bb + col);
    float y0 = (v[j*4+0] - mu) * rstd * gv.x + bv.x;
    float y1 = (v[j*4+1] - mu) * rstd * gv.y + bv.y;
    float y2 = (v[j*4+2] - mu) * rstd * gv.z + bv.z;
    float y3 = (v[j*4+3] - mu) * rstd * gv.w + bv.w;
    v[j*4+0] = y0; v[j*4+1] = y1; v[j*4+2] = y2; v[j*4+3] = y3;
    ss2 += y0*y0 + y1*y1 + y2*y2 + y3*y3;
  }
  ss2 = block_sum_f(ss2);
  const float r2 = 1.0f / sqrtf(ss2 / (float)N + 1e-5f);
  float amax = 0.f;
  #pragma unroll
  for (int i = 0; i < 32; i++) { v[i] *= r2; amax = fmaxf(amax, fabsf(v[i])); }
  amax = block_max_f(amax);
  amax = fmaxf(amax, 1e-5f);
  const float scale = 127.0f / amax;
  #pragma unroll
  for (int j = 0; j < 8; j++) {
    const int col = j * 1024 + t * 4;
    bf16x4 q;
    #pragma unroll
    for (int e = 0; e < 4; e++)
      q[e] = (bf16_t)fminf(fmaxf(rintf(v[j*4+e] * scale), -128.f), 127.f);
    *(bf16x4*)(h + base + col) = q;
  }
  if (t == 0) fh[row] = amax / 127.0f;
}

// ================= 256x256 8-phase GEMM (B stored [N][K]) =================
// 8 waves (2Mx4N), BK=64, 128KiB LDS double-buffer, st_16x32 swizzle,
// piece-retirement staging, counted vmcnt(4), setprio around MFMA.
// Per K-tile t (buffer b=t&1), 4 quadrant phases q=(mh,nh):
//   q0:(0,0) stages A-hi(t+1)   q1:(0,1) stages B-hi(t+1)
//   q2:(1,0) stages A-lo(t+2)   q3:(1,1) stages B-lo(t+2) + vmcnt guard for t+1
template<int EPI, bool STORE_BF16>
__global__ __launch_bounds__(512, 2) void gemm256(const bf16_t* __restrict__ A,
                                                  const bf16_t* __restrict__ B,
                                                  const float* __restrict__ rowf,
                                                  const float* __restrict__ wf,
                                                  const float* __restrict__ bias,
                                                  float* __restrict__ Cf,
                                                  bf16_t* __restrict__ Cb,
                                                  int M, int N, int K) {
  __shared__ bf16_t smem[65536];   // 128 KiB: A[2][16384] then B[2][16384] elems

  const int ntile = N >> 8;
  const int cpx = gridDim.x >> 3;                 // grids are multiples of 8
  const int bid = blockIdx.x;
  const int wg = (bid & 7) * cpx + (bid >> 3);    // XCD-bijective swizzle
  const int bm = wg / ntile, bn = wg % ntile;
  const int tm = bm << 8, tn = bn << 8;

  const int tid = threadIdx.x;
  const int w = tid >> 6, lane = tid & 63;
  const int wm = w >> 2, wn = w & 3;              // 2 x 4 wave grid
  const int ln15 = lane & 15;

  // ---- staging geometry (pre-swizzled global source, linear LDS dest) ----
  const int laneOff = (lane * 16) ^ (lane & 32);  // swz of (lane*16) within 1KB chunk
  const int laneRow = laneOff >> 7;               // 0..7
  const int laneColE = (laneOff & 127) >> 1;      // element col, multiple of 8
  const int cA0 = (w >> 2) * 16384 + (w & 3) * 2048;  // bytes within 32KB A buffer
  const int cB0 = (w >> 1) * 8192 + (w & 1) * 2048;   // bytes within 32KB B buffer

  const bf16_t* pA[2][2]; const bf16_t* pB[2][2];
  #pragma unroll
  for (int h = 0; h < 2; h++)
    #pragma unroll
    for (int j = 0; j < 2; j++) {
      const int ca = cA0 + h * 8192 + j * 1024;
      pA[h][j] = A + (size_t)(tm + (ca >> 7) + laneRow) * K + laneColE;
      const int cb = cB0 + h * 4096 + j * 1024;
      pB[h][j] = B + (size_t)(tn + (cb >> 7) + laneRow) * K + laneColE;
    }
  // wave-uniform LDS dest bases (elements)
  const int dA0 = cA0 >> 1, dB0 = cB0 >> 1;

  // read-side swizzled k offsets (elements): col ^ 16 elems when row&4 (= ln15&4)
  int kswz[2];
  #pragma unroll
  for (int kk = 0; kk < 2; kk++)
    kswz[kk] = (kk * 32 + (lane >> 4) * 8) ^ ((ln15 & 4) << 2);

  f32x4 acc[8][4] = {};
  const int NT = K >> 6;

#define STAGE_A(bb, hh, kt)                                                     \
  { const int k0s = (kt) << 6;                                                  \
    gl_lds16(pA[hh][0] + k0s, smem + (bb) * 16384 + dA0 + (hh) * 4096);         \
    gl_lds16(pA[hh][1] + k0s, smem + (bb) * 16384 + dA0 + (hh) * 4096 + 512); }
#define STAGE_B(bb, hh, kt)                                                     \
  { const int k0s = (kt) << 6;                                                  \
    gl_lds16(pB[hh][0] + k0s, smem + 32768 + (bb) * 16384 + dB0 + (hh) * 2048); \
    gl_lds16(pB[hh][1] + k0s, smem + 32768 + (bb) * 16384 + dB0 + (hh) * 2048 + 512); }

  // ---- prologue: tile0 fully, tile1 lo-halves; wait tile0 ----
  STAGE_A(0, 0, 0); STAGE_B(0, 0, 0); STAGE_A(0, 1, 0); STAGE_B(0, 1, 0);
  STAGE_A(1, 0, 1); STAGE_B(1, 0, 1);
  asm volatile("s_waitcnt vmcnt(4)" ::: "memory");
  __builtin_amdgcn_sched_barrier(0);
  __builtin_amdgcn_s_barrier();
  __builtin_amdgcn_sched_barrier(0);

  for (int t = 0; t < NT; ++t) {
    const int b = t & 1;
    const int abase = b * 16384;
    const int bbase = 32768 + b * 16384;
    #pragma unroll
    for (int q = 0; q < 4; ++q) {
      const int mh = q >> 1, nh = q & 1;
      // ds-load this quadrant's fragments
      bf16x8 af[4][2], bfr[2][2];
      #pragma unroll
      for (int m4 = 0; m4 < 4; m4++)
        #pragma unroll
        for (int kk = 0; kk < 2; kk++)
          af[m4][kk] = *(const bf16x8*)(smem + abase +
                         (wm * 128 + (mh * 4 + m4) * 16 + ln15) * 64 + kswz[kk]);
      #pragma unroll
      for (int n2 = 0; n2 < 2; n2++)
        #pragma unroll
        for (int kk = 0; kk < 2; kk++)
          bfr[n2][kk] = *(const bf16x8*)(smem + bbase +
                         (wn * 64 + (nh * 2 + n2) * 16 + ln15) * 64 + kswz[kk]);
      // stage one retired piece
      if (q == 0)      { if (t + 1 < NT) STAGE_A(b ^ 1, 1, t + 1); }
      else if (q == 1) { if (t + 1 < NT) STAGE_B(b ^ 1, 1, t + 1); }
      else if (q == 2) { if (t + 2 < NT) STAGE_A(b, 0, t + 2); }
      else {
        if (t + 2 < NT) {
          STAGE_B(b, 0, t + 2);
          asm volatile("s_waitcnt vmcnt(4)" ::: "memory");   // guard tile t+1
        } else if (t + 1 < NT) {
          asm volatile("s_waitcnt vmcnt(0)" ::: "memory");   // tail guard
        }
      }
      __builtin_amdgcn_sched_barrier(0);
      __builtin_amdgcn_s_barrier();
      __builtin_amdgcn_sched_barrier(0);
      asm volatile("s_waitcnt lgkmcnt(0)");
      __builtin_amdgcn_sched_barrier(0);
      __builtin_amdgcn_s_setprio(1);
      #pragma unroll
      for (int m4 = 0; m4 < 4; m4++)
        #pragma unroll
        for (int n2 = 0; n2 < 2; n2++)
          #pragma unroll
          for (int kk = 0; kk < 2; kk++)
            acc[mh * 4 + m4][nh * 2 + n2] = __builtin_amdgcn_mfma_f32_16x16x32_bf16(
                af[m4][kk], bfr[n2][kk], acc[mh * 4 + m4][nh * 2 + n2], 0, 0, 0);
      __builtin_amdgcn_s_setprio(0);
      __builtin_amdgcn_sched_barrier(0);
      __builtin_amdgcn_s_barrier();
      __builtin_amdgcn_sched_barrier(0);
    }
  }
#undef STAGE_A
#undef STAGE_B

  // ---- epilogue: dequant + bias (+ SiLU+GELU) ----
  const float fwv = wf[0];
  const int rq = (lane >> 4) << 2;
  float rsc[8][4];
  #pragma unroll
  for (int m = 0; m < 8; m++)
    #pragma unroll
    for (int r = 0; r < 4; r++)
      rsc[m][r] = rowf[tm + wm * 128 + m * 16 + rq + r] * fwv;

  #pragma unroll
  for (int m = 0; m < 8; m++) {
    #pragma unroll
    for (int n = 0; n < 4; n++) {
      const int col = tn + wn * 64 + n * 16 + ln15;
      const float bv = bias[col];
      #pragma unroll
      for (int r = 0; r < 4; r++) {
        const int row = tm + wm * 128 + m * 16 + rq + r;
        float val = acc[m][n][r] * rsc[m][r] + bv;
        if (EPI == 1) {
          float sl = val / (1.0f + expf(-val));                       // SiLU
          val = 0.5f * sl * (1.0f + erff(sl * 0.70710678118654752f)); // exact GELU
        }
        if (STORE_BF16) Cb[(size_t)row * N + col] = (bf16_t)val;
        else            Cf[(size_t)row * N + col] = val;
      }
    }
  }
}

extern "C" void kernel_launch(void* const* d_in, const int* in_sizes, int n_in,
                              void* d_out, int out_size, void* d_ws, size_t ws_size,
                              hipStream_t stream) {
  const float* x   = (const float*)d_in[0];
  const float* w1  = (const float*)d_in[1];
  const float* b1  = (const float*)d_in[2];
  const float* lng = (const float*)d_in[3];
  const float* lnb = (const float*)d_in[4];
  const float* w2  = (const float*)d_in[5];
  const float* b2  = (const float*)d_in[6];
  float* out = (float*)d_out;

  const int inner = in_sizes[2];           // 8192
  const int d     = in_sizes[1] / inner;   // 2048
  const int M     = in_sizes[0] / d;       // 8192

  char* ws = (char*)d_ws;
  size_t off = 0;
  double* part = (double*)(ws + off); off += 1024 * 8;
  float*  fw   = (float*)(ws + off);  off += 256;
  float*  fx   = (float*)(ws + off);  off += (size_t)M * 4;
  float*  fh   = (float*)(ws + off);  off += (size_t)M * 4;
  bf16_t* w1q  = (bf16_t*)(ws + off); off += (size_t)inner * d * 2;
  bf16_t* w2q  = (bf16_t*)(ws + off); off += (size_t)inner * d * 2;

  int MC = M;  // multiple of 256
  while (MC > 256 && off + (size_t)MC * (size_t)(d + inner) * 2 > ws_size) MC >>= 1;
  bf16_t* xq = (bf16_t*)(ws + off); off += (size_t)MC * d * 2;
  bf16_t* hq = (bf16_t*)(ws + off);

  const int nw = inner * d;
  const int n4 = nw / 4;

  wabs_partial<<<1024, 256, 0, stream>>>(w1, n4, part);
  wabs_final<<<1, 256, 0, stream>>>(part, 1024, (double)nw, fw + 0);
  wabs_partial<<<1024, 256, 0, stream>>>(w2, n4, part);
  wabs_final<<<1, 256, 0, stream>>>(part, 1024, (double)nw, fw + 1);
  quant_w<<<n4 / 256, 256, 0, stream>>>(w1, fw + 0, w1q, n4);
  quant_w<<<n4 / 256, 256, 0, stream>>>(w2, fw + 1, w2q, n4);

  for (int mc = 0; mc < M; mc += MC) {
    rms_quant_x<<<MC, 256, 0, stream>>>(x + (size_t)mc * d, xq, fx, d);

    const int g1 = (MC / 256) * (inner / 256);
    gemm256<1, true><<<g1, 512, 0, stream>>>(xq, w1q, fx, fw + 0, b1,
                                             nullptr, hq, MC, inner, d);

    ln_rms_quant<<<MC, 256, 0, stream>>>(hq, lng, lnb, fh, inner);

    const int g2 = (MC / 256) * (d / 256);
    gemm256<0, false><<<g2, 512, 0, stream>>>(hq, w2q, fh, fw + 1, b2,
                                              out + (size_t)mc * d, nullptr, MC, d, inner);
  }
}

// Round 4
// 711.400 us; speedup vs baseline: 1.2747x; 1.1887x over previous
//
#include <hip/hip_runtime.h>
#include <hip/hip_bf16.h>
#include <math.h>

typedef __bf16 bf16_t;
typedef __bf16 bf16x4 __attribute__((ext_vector_type(4)));
typedef __bf16 bf16x8 __attribute__((ext_vector_type(8)));
typedef float f32x4 __attribute__((ext_vector_type(4)));

#define AS1 __attribute__((address_space(1)))
#define AS3 __attribute__((address_space(3)))

__device__ __forceinline__ void gl_lds16(const bf16_t* g, bf16_t* l) {
  __builtin_amdgcn_global_load_lds((const AS1 void*)g, (AS3 void*)l, 16, 0, 0);
}

// ---------- block reductions (256 threads = 4 waves) ----------
__device__ __forceinline__ float block_sum_f(float v) {
  __shared__ float sb[4];
  #pragma unroll
  for (int o = 32; o; o >>= 1) v += __shfl_xor(v, o);
  if ((threadIdx.x & 63) == 0) sb[threadIdx.x >> 6] = v;
  __syncthreads();
  v = sb[0] + sb[1] + sb[2] + sb[3];
  __syncthreads();
  return v;
}
__device__ __forceinline__ float block_max_f(float v) {
  __shared__ float sm[4];
  #pragma unroll
  for (int o = 32; o; o >>= 1) v = fmaxf(v, __shfl_xor(v, o));
  if ((threadIdx.x & 63) == 0) sm[threadIdx.x >> 6] = v;
  __syncthreads();
  v = fmaxf(fmaxf(sm[0], sm[1]), fmaxf(sm[2], sm[3]));
  __syncthreads();
  return v;
}

// ---------- weight absmean (f64 accumulation, two-pass, deterministic) ----------
__global__ __launch_bounds__(256) void wabs_partial(const float* __restrict__ w, int n4,
                                                    double* __restrict__ part) {
  const float4* w4 = (const float4*)w;
  double s = 0.0;
  const int stride = gridDim.x * blockDim.x;
  for (int i = blockIdx.x * blockDim.x + threadIdx.x; i < n4; i += stride) {
    float4 v = w4[i];
    s += (double)fabsf(v.x) + (double)fabsf(v.y) + (double)fabsf(v.z) + (double)fabsf(v.w);
  }
  #pragma unroll
  for (int o = 32; o; o >>= 1) s += __shfl_xor(s, o);
  __shared__ double sd[4];
  if ((threadIdx.x & 63) == 0) sd[threadIdx.x >> 6] = s;
  __syncthreads();
  if (threadIdx.x == 0) part[blockIdx.x] = sd[0] + sd[1] + sd[2] + sd[3];
}

__global__ __launch_bounds__(256) void wabs_final(const double* __restrict__ part, int np,
                                                  double n, float* __restrict__ fwout) {
  double s = 0.0;
  for (int i = threadIdx.x; i < np; i += blockDim.x) s += part[i];
  #pragma unroll
  for (int o = 32; o; o >>= 1) s += __shfl_xor(s, o);
  __shared__ double sd[4];
  if ((threadIdx.x & 63) == 0) sd[threadIdx.x >> 6] = s;
  __syncthreads();
  if (threadIdx.x == 0) {
    double mean = (sd[0] + sd[1] + sd[2] + sd[3]) / n;
    fwout[0] = (float)fmax(mean, 1e-5);
  }
}

// ---------- ternary weight quantization ----------
__global__ __launch_bounds__(256) void quant_w(const float* __restrict__ w,
                                               const float* __restrict__ fw,
                                               bf16_t* __restrict__ wq, int n4) {
  int i = blockIdx.x * blockDim.x + threadIdx.x;
  if (i >= n4) return;
  const float s = 1.0f / fw[0];
  float4 v = ((const float4*)w)[i];
  bf16x4 q;
  q[0] = (bf16_t)fminf(fmaxf(rintf(v.x * s), -1.f), 1.f);
  q[1] = (bf16_t)fminf(fmaxf(rintf(v.y * s), -1.f), 1.f);
  q[2] = (bf16_t)fminf(fmaxf(rintf(v.z * s), -1.f), 1.f);
  q[3] = (bf16_t)fminf(fmaxf(rintf(v.w * s), -1.f), 1.f);
  ((bf16x4*)wq)[i] = q;
}

// ---------- rms_norm + act_quant of x rows (K = 2048) ----------
__global__ __launch_bounds__(256) void rms_quant_x(const float* __restrict__ x,
                                                   bf16_t* __restrict__ xq,
                                                   float* __restrict__ fx, int K) {
  const int row = blockIdx.x, t = threadIdx.x;
  const size_t base = (size_t)row * K;
  float v[8];
  float ss = 0.f;
  #pragma unroll
  for (int j = 0; j < 2; j++) {
    float4 lv = *(const float4*)(x + base + j * 1024 + t * 4);
    v[j*4+0] = lv.x; v[j*4+1] = lv.y; v[j*4+2] = lv.z; v[j*4+3] = lv.w;
  }
  #pragma unroll
  for (int i = 0; i < 8; i++) ss += v[i] * v[i];
  ss = block_sum_f(ss);
  const float r = 1.0f / sqrtf(ss / (float)K + 1e-5f);
  float amax = 0.f;
  #pragma unroll
  for (int i = 0; i < 8; i++) { v[i] *= r; amax = fmaxf(amax, fabsf(v[i])); }
  amax = block_max_f(amax);
  amax = fmaxf(amax, 1e-5f);
  const float scale = 127.0f / amax;
  #pragma unroll
  for (int j = 0; j < 2; j++) {
    bf16x4 q;
    #pragma unroll
    for (int e = 0; e < 4; e++)
      q[e] = (bf16_t)fminf(fmaxf(rintf(v[j*4+e] * scale), -128.f), 127.f);
    *(bf16x4*)(xq + base + j * 1024 + t * 4) = q;
  }
  if (t == 0) fx[row] = amax / 127.0f;
}

// ---------- LayerNorm -> rms_norm -> act_quant, IN-PLACE on bf16 h rows (N = 8192) ----
__global__ __launch_bounds__(256) void ln_rms_quant(bf16_t* h,
                                                    const float* __restrict__ g,
                                                    const float* __restrict__ bb,
                                                    float* __restrict__ fh, int N) {
  const int row = blockIdx.x, t = threadIdx.x;
  const size_t base = (size_t)row * N;
  float v[32];
  float s = 0.f, ss = 0.f;
  #pragma unroll
  for (int j = 0; j < 8; j++) {
    const int col = j * 1024 + t * 4;
    bf16x4 q = *(const bf16x4*)(h + base + col);
    v[j*4+0] = (float)q[0]; v[j*4+1] = (float)q[1];
    v[j*4+2] = (float)q[2]; v[j*4+3] = (float)q[3];
  }
  #pragma unroll
  for (int i = 0; i < 32; i++) { s += v[i]; ss += v[i] * v[i]; }
  s = block_sum_f(s);
  ss = block_sum_f(ss);
  const float mu = s / (float)N;
  const float var = ss / (float)N - mu * mu;
  const float rstd = 1.0f / sqrtf(var + 1e-5f);
  float ss2 = 0.f;
  #pragma unroll
  for (int j = 0; j < 8; j++) {
    const int col = j * 1024 + t * 4;
    float4 gv = *(const float4*)(g + col);
    float4 bv = *(const float4*)(bb + col);
    float y0 = (v[j*4+0] - mu) * rstd * gv.x + bv.x;
    float y1 = (v[j*4+1] - mu) * rstd * gv.y + bv.y;
    float y2 = (v[j*4+2] - mu) * rstd * gv.z + bv.z;
    float y3 = (v[j*4+3] - mu) * rstd * gv.w + bv.w;
    v[j*4+0] = y0; v[j*4+1] = y1; v[j*4+2] = y2; v[j*4+3] = y3;
    ss2 += y0*y0 + y1*y1 + y2*y2 + y3*y3;
  }
  ss2 = block_sum_f(ss2);
  const float r2 = 1.0f / sqrtf(ss2 / (float)N + 1e-5f);
  float amax = 0.f;
  #pragma unroll
  for (int i = 0; i < 32; i++) { v[i] *= r2; amax = fmaxf(amax, fabsf(v[i])); }
  amax = block_max_f(amax);
  amax = fmaxf(amax, 1e-5f);
  const float scale = 127.0f / amax;
  #pragma unroll
  for (int j = 0; j < 8; j++) {
    const int col = j * 1024 + t * 4;
    bf16x4 q;
    #pragma unroll
    for (int e = 0; e < 4; e++)
      q[e] = (bf16_t)fminf(fmaxf(rintf(v[j*4+e] * scale), -128.f), 127.f);
    *(bf16x4*)(h + base + col) = q;
  }
  if (t == 0) fh[row] = amax / 127.0f;
}

// ================= 256x256 8-phase GEMM (B stored [N][K]) =================
// 8 waves (2Mx4N). BK=64. LDS: per buffer, A = 16 subtiles [16 rows][2 kk][16][32]
// (1KB subtile, elem idx = rowblk*1024 + kk*512 + r16*32 + (col ^ swz(r16))),
// swz(r16) = (r16&8?16:0)^(r16&4?8:0)  -> quarter-wave ds_read_b128 is 2-way (free).
// Quadrant order per K-tile: (mh,nh) = (0,0),(1,0),(1,1),(0,1); A frags (16) held
// across the tile, B frags (4) per half. Stages: q0 Bhi(t+1), q1 Alo(t+2),
// q2 Ahi(t+2), q3 Blo(t+2); guards vmcnt(10)@q1, vmcnt(8)@q3 (counted, exact tails).
template<int EPI, bool STORE_BF16>
__global__ __launch_bounds__(512, 2) void gemm256(const bf16_t* __restrict__ A,
                                                  const bf16_t* __restrict__ B,
                                                  const float* __restrict__ rowf,
                                                  const float* __restrict__ wf,
                                                  const float* __restrict__ bias,
                                                  float* __restrict__ Cf,
                                                  bf16_t* __restrict__ Cb,
                                                  int M, int N, int K) {
  __shared__ bf16_t smem[65536];   // A[2][16384] then B[2][16384] elements

  const int ntile = N >> 8;
  const int cpx = gridDim.x >> 3;
  const int bid = blockIdx.x;
  const int wg = (bid & 7) * cpx + (bid >> 3);    // XCD-bijective swizzle
  const int bm = wg / ntile, bn = wg % ntile;
  const int tm = bm << 8, tn = bn << 8;

  const int tid = threadIdx.x;
  const int w = tid >> 6, lane = tid & 63;
  const int wm = w >> 2, wn = w & 3;              // 2 x 4 wave grid
  const int ln15 = lane & 15;

  // ---- staging: wave w owns rowblk w (lo) / 8+w (hi), lane covers subtile linearly;
  // source col pre-swizzled so linear LDS dest yields swizzled content.
  const int srcRow = lane >> 2;                                   // 0..15
  const int srcCol = ((lane & 3) * 8) ^ ((lane & 32) ? 16 : 0) ^ ((lane & 16) ? 8 : 0);
  const size_t KS = (size_t)K;
  const bf16_t* pAb = A + (size_t)(tm + w * 16 + srcRow) * KS + srcCol;
  const bf16_t* pBb = B + (size_t)(tn + w * 16 + srcRow) * KS + srcCol;
  const size_t hiO = (size_t)128 * KS;            // +128 rows for the hi half
  const int dA = w * 1024;                        // dest elem offset of wave's subtile

  // ---- fragment read offset within a subtile (swizzled) ----
  const int kcr = ((lane >> 4) * 8) ^ ((ln15 & 8) ? 16 : 0) ^ ((ln15 & 4) ? 8 : 0);
  const int foff = ln15 * 32 + kcr;

  f32x4 acc[8][4] = {};
  const int NT = K >> 6;

#define SB __builtin_amdgcn_sched_barrier(0)
#define BAR { SB; __builtin_amdgcn_s_barrier(); SB; }
#define LGKM0 { asm volatile("s_waitcnt lgkmcnt(0)" ::: "memory"); SB; }
#define ST_ALO(bb, kt) { const bf16_t* p = pAb + (size_t)(kt) * 64;        \
    gl_lds16(p,      smem + (bb) * 16384 + dA);                            \
    gl_lds16(p + 32, smem + (bb) * 16384 + dA + 512); }
#define ST_AHI(bb, kt) { const bf16_t* p = pAb + hiO + (size_t)(kt) * 64;  \
    gl_lds16(p,      smem + (bb) * 16384 + 8192 + dA);                     \
    gl_lds16(p + 32, smem + (bb) * 16384 + 8192 + dA + 512); }
#define ST_BLO(bb, kt) { const bf16_t* p = pBb + (size_t)(kt) * 64;        \
    gl_lds16(p,      smem + 32768 + (bb) * 16384 + dA);                    \
    gl_lds16(p + 32, smem + 32768 + (bb) * 16384 + dA + 512); }
#define ST_BHI(bb, kt) { const bf16_t* p = pBb + hiO + (size_t)(kt) * 64;  \
    gl_lds16(p,      smem + 32768 + (bb) * 16384 + 8192 + dA);             \
    gl_lds16(p + 32, smem + 32768 + (bb) * 16384 + 8192 + dA + 512); }
#define MM(AF, MB, NB)                                                     \
  _Pragma("unroll") for (int m4 = 0; m4 < 4; m4++)                         \
    _Pragma("unroll") for (int n2 = 0; n2 < 2; n2++)                       \
      _Pragma("unroll") for (int kk = 0; kk < 2; kk++)                     \
        acc[(MB)+m4][(NB)+n2] = __builtin_amdgcn_mfma_f32_16x16x32_bf16(   \
            AF[m4][kk], bfr[n2][kk], acc[(MB)+m4][(NB)+n2], 0, 0, 0);

  // ---- prologue: tile0 all pieces, tile1 Alo/Ahi/Blo (Bhi(1) staged at t0 q0) ----
  ST_ALO(0, 0); ST_AHI(0, 0); ST_BLO(0, 0); ST_BHI(0, 0);
  ST_ALO(1, 1); ST_AHI(1, 1); ST_BLO(1, 1);
  asm volatile("s_waitcnt vmcnt(8)" ::: "memory");   // Alo0/Ahi0/Blo0 landed
  BAR;

  bf16x8 afL[4][2], afH[4][2], bfr[2][2];
  for (int t = 0; t < NT; ++t) {
    const int b = t & 1;
    const bf16_t* sA = smem + b * 16384;
    const bf16_t* sB = smem + 32768 + b * 16384;
    // ---- q0: (mh0, nh0) — read A-lo(8) + B-lo(4)
    #pragma unroll
    for (int m4 = 0; m4 < 4; m4++)
      #pragma unroll
      for (int kk = 0; kk < 2; kk++)
        afL[m4][kk] = *(const bf16x8*)(sA + (wm * 4 + m4) * 1024 + kk * 512 + foff);
    #pragma unroll
    for (int n2 = 0; n2 < 2; n2++)
      #pragma unroll
      for (int kk = 0; kk < 2; kk++)
        bfr[n2][kk] = *(const bf16x8*)(sB + (wn * 2 + n2) * 1024 + kk * 512 + foff);
    if (t + 1 < NT) ST_BHI(b ^ 1, t + 1);
    BAR; LGKM0;
    __builtin_amdgcn_s_setprio(1);
    MM(afL, 0, 0);
    __builtin_amdgcn_s_setprio(0);
    BAR;
    // ---- q1: (mh1, nh0) — read A-hi(8)
    #pragma unroll
    for (int m4 = 0; m4 < 4; m4++)
      #pragma unroll
      for (int kk = 0; kk < 2; kk++)
        afH[m4][kk] = *(const bf16x8*)(sA + 8192 + (wm * 4 + m4) * 1024 + kk * 512 + foff);
    if (t + 2 < NT) {
      ST_ALO(b, t + 2);
      asm volatile("s_waitcnt vmcnt(10)" ::: "memory");      // Bhi(t) landed
    } else if (t + 1 < NT) {
      asm volatile("s_waitcnt vmcnt(8)" ::: "memory");
    } else {
      asm volatile("s_waitcnt vmcnt(0)" ::: "memory");
    }
    BAR; LGKM0;
    __builtin_amdgcn_s_setprio(1);
    MM(afH, 4, 0);
    __builtin_amdgcn_s_setprio(0);
    BAR;
    // ---- q2: (mh1, nh1) — read B-hi(4)
    #pragma unroll
    for (int n2 = 0; n2 < 2; n2++)
      #pragma unroll
      for (int kk = 0; kk < 2; kk++)
        bfr[n2][kk] = *(const bf16x8*)(sB + 8192 + (wn * 2 + n2) * 1024 + kk * 512 + foff);
    if (t + 2 < NT) ST_AHI(b, t + 2);
    BAR; LGKM0;
    __builtin_amdgcn_s_setprio(1);
    MM(afH, 4, 2);
    __builtin_amdgcn_s_setprio(0);
    BAR;
    // ---- q3: (mh0, nh1) — no ds_reads
    if (t + 2 < NT) {
      ST_BLO(b, t + 2);
      asm volatile("s_waitcnt vmcnt(8)" ::: "memory");       // Alo/Ahi/Blo(t+1) landed
    } else if (t + 1 < NT) {
      asm volatile("s_waitcnt vmcnt(2)" ::: "memory");
    }
    BAR;
    __builtin_amdgcn_s_setprio(1);
    MM(afL, 0, 2);
    __builtin_amdgcn_s_setprio(0);
    BAR;
  }
#undef ST_ALO
#undef ST_AHI
#undef ST_BLO
#undef ST_BHI
#undef MM

  // ---- epilogue: dequant + bias (+ SiLU+GELU) ----
  const float fwv = wf[0];
  const int rq = (lane >> 4) << 2;
  float rsc[8][4];
  #pragma unroll
  for (int m = 0; m < 8; m++)
    #pragma unroll
    for (int r = 0; r < 4; r++)
      rsc[m][r] = rowf[tm + (m >> 2) * 128 + wm * 64 + (m & 3) * 16 + rq + r] * fwv;

  #pragma unroll
  for (int m = 0; m < 8; m++) {
    #pragma unroll
    for (int n = 0; n < 4; n++) {
      const int col = tn + (n >> 1) * 128 + wn * 32 + (n & 1) * 16 + ln15;
      const float bv = bias[col];
      #pragma unroll
      for (int r = 0; r < 4; r++) {
        const int row = tm + (m >> 2) * 128 + wm * 64 + (m & 3) * 16 + rq + r;
        float val = acc[m][n][r] * rsc[m][r] + bv;
        if (EPI == 1) {
          float sl = val / (1.0f + expf(-val));                       // SiLU
          val = 0.5f * sl * (1.0f + erff(sl * 0.70710678118654752f)); // exact GELU
        }
        if (STORE_BF16) Cb[(size_t)row * N + col] = (bf16_t)val;
        else            Cf[(size_t)row * N + col] = val;
      }
    }
  }
}

extern "C" void kernel_launch(void* const* d_in, const int* in_sizes, int n_in,
                              void* d_out, int out_size, void* d_ws, size_t ws_size,
                              hipStream_t stream) {
  const float* x   = (const float*)d_in[0];
  const float* w1  = (const float*)d_in[1];
  const float* b1  = (const float*)d_in[2];
  const float* lng = (const float*)d_in[3];
  const float* lnb = (const float*)d_in[4];
  const float* w2  = (const float*)d_in[5];
  const float* b2  = (const float*)d_in[6];
  float* out = (float*)d_out;

  const int inner = in_sizes[2];           // 8192
  const int d     = in_sizes[1] / inner;   // 2048
  const int M     = in_sizes[0] / d;       // 8192

  char* ws = (char*)d_ws;
  size_t off = 0;
  double* part = (double*)(ws + off); off += 1024 * 8;
  float*  fw   = (float*)(ws + off);  off += 256;
  float*  fx   = (float*)(ws + off);  off += (size_t)M * 4;
  float*  fh   = (float*)(ws + off);  off += (size_t)M * 4;
  bf16_t* w1q  = (bf16_t*)(ws + off); off += (size_t)inner * d * 2;
  bf16_t* w2q  = (bf16_t*)(ws + off); off += (size_t)inner * d * 2;

  int MC = M;  // multiple of 256
  while (MC > 256 && off + (size_t)MC * (size_t)(d + inner) * 2 > ws_size) MC >>= 1;
  bf16_t* xq = (bf16_t*)(ws + off); off += (size_t)MC * d * 2;
  bf16_t* hq = (bf16_t*)(ws + off);

  const int nw = inner * d;
  const int n4 = nw / 4;

  wabs_partial<<<1024, 256, 0, stream>>>(w1, n4, part);
  wabs_final<<<1, 256, 0, stream>>>(part, 1024, (double)nw, fw + 0);
  wabs_partial<<<1024, 256, 0, stream>>>(w2, n4, part);
  wabs_final<<<1, 256, 0, stream>>>(part, 1024, (double)nw, fw + 1);
  quant_w<<<n4 / 256, 256, 0, stream>>>(w1, fw + 0, w1q, n4);
  quant_w<<<n4 / 256, 256, 0, stream>>>(w2, fw + 1, w2q, n4);

  for (int mc = 0; mc < M; mc += MC) {
    rms_quant_x<<<MC, 256, 0, stream>>>(x + (size_t)mc * d, xq, fx, d);

    const int g1 = (MC / 256) * (inner / 256);
    gemm256<1, true><<<g1, 512, 0, stream>>>(xq, w1q, fx, fw + 0, b1,
                                             nullptr, hq, MC, inner, d);

    ln_rms_quant<<<MC, 256, 0, stream>>>(hq, lng, lnb, fh, inner);

    const int g2 = (MC / 256) * (d / 256);
    gemm256<0, false><<<g2, 512, 0, stream>>>(hq, w2q, fh, fw + 1, b2,
                                              out + (size_t)mc * d, nullptr, MC, d, inner);
  }
}